// Round 9
// baseline (125.715 us; speedup 1.0000x reference)
//
#include <hip/hip_runtime.h>

// Problem: B,H,W,D = 64,32,32,64 ; K=1024 ; N = 65536
#define NPTS   65536
#define DDIM   64
#define KCODES 1024
#define QOUT_ELEMS (NPTS * DDIM)

typedef _Float16 half8    __attribute__((ext_vector_type(8)));
typedef float    floatx16 __attribute__((ext_vector_type(16)));
typedef unsigned int uint;

// ws: eh [0,128K) chunk-major f16 | el [128K,256K) | e2 f32 [256K,260K)
#define WS_EHP   0
#define WS_ELP   (128*1024)
#define WS_E2F   (256*1024)

// ---------------------------------------------------------------------------
// eprep (verified r8): one wave per code. e -> f16 hi/lo chunk-major + ||e||^2.
// chunk-major: tile T=k>>5, chunk j=d>>3, c=k&31: off = T*4096+j*512+c*16+(d&7)*2
// ---------------------------------------------------------------------------
__global__ void eprep_kernel(const float* __restrict__ emb, char* __restrict__ ws) {
    const int tid = threadIdx.x;
    const int w = tid >> 6, d = tid & 63;
    const int k = blockIdx.x * 4 + w;
    float v = emb[(size_t)k * DDIM + d];
    _Float16 h = (_Float16)v;
    _Float16 l = (_Float16)(v - (float)h);
    size_t off = (size_t)(k >> 5) * 4096 + (size_t)(d >> 3) * 512
               + (size_t)(k & 31) * 16 + (size_t)(d & 7) * 2;
    *(_Float16*)(ws + WS_EHP + off) = h;
    *(_Float16*)(ws + WS_ELP + off) = l;
    float s = v * v;
    #pragma unroll
    for (int m = 1; m < 64; m <<= 1) s += __shfl_xor(s, m, 64);
    if (d == 0) ((float*)(ws + WS_E2F))[k] = s;
}

#define MFMA __builtin_amdgcn_mfma_f32_32x32x16_f16

// load one 32-code tile's B fragments (hi+lo) + e2 — all straight from L2
#define LOAD_TILE(BH, BL, E2V, tt) do {                                       \
    const char* _p = ws_c + WS_EHP + (size_t)(tt) * 4096 + sel8 * 512 + col * 16; \
    _Pragma("unroll") for (int _k = 0; _k < 4; ++_k)                          \
        BH[_k] = *(const half8*)(_p + _k * 1024);                             \
    _Pragma("unroll") for (int _k = 0; _k < 4; ++_k)                          \
        BL[_k] = *(const half8*)(_p + (WS_ELP - WS_EHP) + _k * 1024);         \
    E2V = e2f[(tt) * 32 + col];                                               \
} while (0)

// 12-MFMA chain (hh x4, hl x4, lh x4) + fused running argmin (score = acc+e2)
#define DO_TILE(BH, BL, E2V, TCUR) do {                                       \
    floatx16 acc;                                                             \
    acc = MFMA(ah[0], BH[0], zeroC, 0, 0, 0);                                 \
    acc = MFMA(ah[1], BH[1], acc, 0, 0, 0);                                   \
    acc = MFMA(ah[2], BH[2], acc, 0, 0, 0);                                   \
    acc = MFMA(ah[3], BH[3], acc, 0, 0, 0);                                   \
    acc = MFMA(ah[0], BL[0], acc, 0, 0, 0);                                   \
    acc = MFMA(ah[1], BL[1], acc, 0, 0, 0);                                   \
    acc = MFMA(ah[2], BL[2], acc, 0, 0, 0);                                   \
    acc = MFMA(ah[3], BL[3], acc, 0, 0, 0);                                   \
    acc = MFMA(al[0], BH[0], acc, 0, 0, 0);                                   \
    acc = MFMA(al[1], BH[1], acc, 0, 0, 0);                                   \
    acc = MFMA(al[2], BH[2], acc, 0, 0, 0);                                   \
    acc = MFMA(al[3], BH[3], acc, 0, 0, 0);                                   \
    const int vcode = (TCUR) * 32 + col;                                      \
    _Pragma("unroll") for (int _r = 0; _r < 16; ++_r) {                       \
        float _s = acc[_r] + (E2V);                                           \
        bool _c = _s < best[_r];       /* strict <: earliest code wins ties */ \
        best[_r]  = _c ? _s    : best[_r];                                    \
        bcode[_r] = _c ? vcode : bcode[_r];                                   \
    }                                                                         \
} while (0)

// ---------------------------------------------------------------------------
// Main: 2048 blocks x 64 thr = 2048 independent waves, NO LDS, NO barriers.
// Wave = 32 points (blockIdx*32 + col) x ALL 1024 codes (32 tiles), B-frags
// streamed from L2 into ping-pong register sets, one-tile prefetch depth.
// 8 waves/CU — all resident in one generation; MFMA floor 10.2 us.
// Layouts (verified r2..r8): A[m=lane&31][k=sel8*8+j]; B same (n=lane&31);
// C/D: col=lane&31 (code), row=(r&3)+8*(r>>2)+4*sel8 (point).
// ---------------------------------------------------------------------------
__global__ __launch_bounds__(64, 2) void vq_kernel(
    const float* __restrict__ z,
    const char* __restrict__ ws_c,
    const float* __restrict__ emb,
    float* __restrict__ out)
{
    const int lane = threadIdx.x & 63;
    const int col  = lane & 31;
    const int sel8 = lane >> 5;
    const int ptbase = blockIdx.x * 32;
    const float* e2f = (const float*)(ws_c + WS_E2F);

    // ---- A fragments: a = -2 z[pt], hi/lo fp16 ----
    half8 ah[4], al[4];
    {
        const float* zrow = z + (size_t)(ptbase + col) * DDIM + sel8 * 8;
        #pragma unroll
        for (int ks = 0; ks < 4; ++ks) {
            float4 u0 = *(const float4*)(zrow + ks * 16);
            float4 u1 = *(const float4*)(zrow + ks * 16 + 4);
            float tv[8] = {u0.x, u0.y, u0.z, u0.w, u1.x, u1.y, u1.z, u1.w};
            #pragma unroll
            for (int j = 0; j < 8; ++j) {
                float a = -2.0f * tv[j];
                _Float16 hh = (_Float16)a;
                ah[ks][j] = hh;
                al[ks][j] = (_Float16)(a - (float)hh);
            }
        }
    }

    const floatx16 zeroC = {};
    float best[16];
    int   bcode[16];
    #pragma unroll
    for (int r = 0; r < 16; ++r) { best[r] = 3.4e38f; bcode[r] = 0; }

    // ---- ping-pong streamed K-loop: 32 tiles, prefetch depth 1 ----
    half8 b0h[4], b0l[4], b1h[4], b1l[4];
    float e20, e21;
    LOAD_TILE(b0h, b0l, e20, 0);
    for (int t = 0; t < 32; t += 2) {
        LOAD_TILE(b1h, b1l, e21, t + 1);
        DO_TILE(b0h, b0l, e20, t);
        const int t2 = (t + 2 < 32) ? t + 2 : 31;   // last prefetch harmless
        LOAD_TILE(b0h, b0l, e20, t2);
        DO_TILE(b1h, b1l, e21, t + 1);
    }

    // ---- butterfly argmin across the 32 code-columns (within sel8 group) ----
    #pragma unroll
    for (int m = 1; m < 32; m <<= 1) {
        #pragma unroll
        for (int r = 0; r < 16; ++r) {
            float ov = __shfl_xor(best[r],  m, 64);
            int   oc = __shfl_xor(bcode[r], m, 64);
            bool c = (ov < best[r]) || (ov == best[r] && oc < bcode[r]);
            best[r]  = c ? ov : best[r];
            bcode[r] = c ? oc : bcode[r];
        }
    }

    // ---- epilogue: every lane holds the final codes for its 16 point-rows ----
    #pragma unroll
    for (int r = 0; r < 16; ++r) {
        int row = (r & 3) + 8 * (r >> 2) + 4 * sel8;
        int p = ptbase + row;
        int code = bcode[r];
        // quantized: the 32 lanes of this col-group write the point's 64 floats
        float2 v = ((const float2*)emb)[(size_t)code * 32 + col];
        ((float2*)out)[(size_t)p * 32 + col] = v;
        if (col == 0) out[QOUT_ELEMS + p] = (float)code;
    }
}

extern "C" void kernel_launch(void* const* d_in, const int* in_sizes, int n_in,
                              void* d_out, int out_size, void* d_ws, size_t ws_size,
                              hipStream_t stream) {
    const float* z   = (const float*)d_in[0];
    const float* emb = (const float*)d_in[1];
    float* out = (float*)d_out;
    char* ws = (char*)d_ws;

    eprep_kernel<<<KCODES / 4, 256, 0, stream>>>(emb, ws);
    vq_kernel<<<NPTS / 32, 64, 0, stream>>>(z, ws, emb, out);
}